// Round 5
// baseline (46.946 us; speedup 1.0000x reference)
//
#include <hip/hip_runtime.h>
#include <hip/hip_bf16.h>

// Problem constants (from reference)
#define VOCAB   128000
#define DIM     2048
#define N_TRAIN 256
#define N_TOKENS (4 * 4096)   // BATCH * SEQ
#define ROWS_PER_BLOCK 4

typedef float f32x4 __attribute__((ext_vector_type(4)));

// One block (256 threads) per 4 output rows. All 8 W-row loads per thread
// are issued before any dependent work (deep MLP); trained-token match is
// per-wave ballot under the load shadow (no LDS, no barrier).
// out[row, :] = W[t, :] + sum over k with token_indices[k]==t of delta_rows[k, :]
// delta layout: delta_rows[k][c] = delta[c * N_TRAIN + k]
__global__ __launch_bounds__(256) void gather_adapted_rows(
    const int* __restrict__ x,          // [N_TOKENS]
    const float* __restrict__ W,        // [VOCAB, DIM]
    const float* __restrict__ delta,    // [DIM * N_TRAIN] col-major (k fast)
    const int* __restrict__ tok_idx,    // [N_TRAIN]
    float* __restrict__ out)            // [N_TOKENS, DIM]
{
    const int base_row = blockIdx.x * ROWS_PER_BLOCK;
    const int tid = threadIdx.x;
    const int lane = tid & 63;
    const int f4a = tid;          // 0..255
    const int f4b = tid + 256;    // 256..511

    // 4 independent token loads first (uniform -> scalar loads).
    int t[ROWS_PER_BLOCK];
    #pragma unroll
    for (int r = 0; r < ROWS_PER_BLOCK; ++r) t[r] = x[base_row + r];

    // Issue all 8 16B W loads back-to-back: 8 outstanding vmem ops/thread.
    f32x4 va[ROWS_PER_BLOCK], vb[ROWS_PER_BLOCK];
    #pragma unroll
    for (int r = 0; r < ROWS_PER_BLOCK; ++r) {
        const f32x4* wrow4 = reinterpret_cast<const f32x4*>(W + (size_t)t[r] * DIM);
        va[r] = wrow4[f4a];
        vb[r] = wrow4[f4b];
    }

    // tok_idx loaded ONCE (L2-resident, 1 KiB), compared against each row's t.
    const int tk0 = tok_idx[lane];
    const int tk1 = tok_idx[lane +  64];
    const int tk2 = tok_idx[lane + 128];
    const int tk3 = tok_idx[lane + 192];

    #pragma unroll
    for (int r = 0; r < ROWS_PER_BLOCK; ++r) {
        unsigned long long m0 = __ballot(tk0 == t[r]);
        unsigned long long m1 = __ballot(tk1 == t[r]);
        unsigned long long m2 = __ballot(tk2 == t[r]);
        unsigned long long m3 = __ballot(tk3 == t[r]);
        if (m0 | m1 | m2 | m3) {
            // Rare (~33/16384 rows): accumulate every matched delta row k.
            unsigned long long masks[4] = {m0, m1, m2, m3};
            #pragma unroll
            for (int j = 0; j < 4; ++j) {
                unsigned long long m = masks[j];
                while (m) {
                    const int l = __builtin_ctzll(m);
                    m &= m - 1;
                    const int k = 64 * j + l;
                    const int ca = f4a * 4;
                    va[r].x += delta[(size_t)(ca + 0) * N_TRAIN + k];
                    va[r].y += delta[(size_t)(ca + 1) * N_TRAIN + k];
                    va[r].z += delta[(size_t)(ca + 2) * N_TRAIN + k];
                    va[r].w += delta[(size_t)(ca + 3) * N_TRAIN + k];
                    const int cb = f4b * 4;
                    vb[r].x += delta[(size_t)(cb + 0) * N_TRAIN + k];
                    vb[r].y += delta[(size_t)(cb + 1) * N_TRAIN + k];
                    vb[r].z += delta[(size_t)(cb + 2) * N_TRAIN + k];
                    vb[r].w += delta[(size_t)(cb + 3) * N_TRAIN + k];
                }
            }
        }
    }

    #pragma unroll
    for (int r = 0; r < ROWS_PER_BLOCK; ++r) {
        f32x4* orow4 = reinterpret_cast<f32x4*>(out + (size_t)(base_row + r) * DIM);
        __builtin_nontemporal_store(va[r], &orow4[f4a]);
        __builtin_nontemporal_store(vb[r], &orow4[f4b]);
    }
}

extern "C" void kernel_launch(void* const* d_in, const int* in_sizes, int n_in,
                              void* d_out, int out_size, void* d_ws, size_t ws_size,
                              hipStream_t stream) {
    const int*   x       = (const int*)  d_in[0];  // [16384]
    const float* W       = (const float*)d_in[1];  // [128000*2048]
    const float* delta   = (const float*)d_in[2];  // [2048*256]
    const int*   tok_idx = (const int*)  d_in[3];  // [256]
    float* out = (float*)d_out;

    dim3 grid(N_TOKENS / ROWS_PER_BLOCK);
    dim3 block(256);
    gather_adapted_rows<<<grid, block, 0, stream>>>(x, W, delta, tok_idx, out);
}